// Round 1
// baseline (2001.714 us; speedup 1.0000x reference)
//
#include <hip/hip_runtime.h>
#include <hip/hip_bf16.h>

// LSTM: B=64, T=2048, D=128, H=128, gates 4H=512.
// Kernel 1: xg[b][t][g] = sum_d x[b,t,d]*Wx[d,g] + bias[g]   (parallel GEMM)
// Kernel 2: per-batch sequential recurrence, 1 block per batch element.

#define B_ 64
#define T_ 2048
#define D_ 128
#define H_ 128
#define G_ 512  // 4*H

__device__ __forceinline__ float fast_exp2(float x) { return __builtin_amdgcn_exp2f(x); }
__device__ __forceinline__ float fast_rcp(float x)  { return __builtin_amdgcn_rcpf(x); }
__device__ __forceinline__ float sigmoid_(float x) {
    // 1/(1+e^-x) = 1/(1+2^(-x*log2e))
    return fast_rcp(1.0f + fast_exp2(x * -1.44269504088896341f));
}
__device__ __forceinline__ float tanh_(float x) {
    // tanh(x) = 1 - 2/(1+e^{2x});  e^{2x} = 2^(x*2*log2e). inf/0 limits give +-1 correctly.
    return 1.0f - 2.0f * fast_rcp(1.0f + fast_exp2(x * 2.88539008177792682f));
}

// ---------------- Kernel 1: input projection GEMM ----------------
// grid: (B*C)/64 blocks of 256 threads; each block computes 64 rows x 512 cols.
// Rows are (b, t_local) within the current chunk [t0, t0+C); C is a multiple of 64
// so a 64-row tile never straddles a batch boundary.
__global__ void __launch_bounds__(256, 2)
xg_gemm_kernel(const float* __restrict__ x, const float* __restrict__ Wx,
               const float* __restrict__ bias, float* __restrict__ xg,
               int t0, int C) {
    __shared__ float xs[64 * 128];  // 32 KB: 64 rows of x
    const int tid = threadIdx.x;
    const int block_row = blockIdx.x * 64;   // row index in [0, B*C)
    const int b  = block_row / C;
    const int tl = block_row - b * C;

    // stage x tile (contiguous 32 KB) into LDS
    const float* xrow = x + ((size_t)b * T_ + (size_t)(t0 + tl)) * D_;
    const float4* xv = (const float4*)xrow;
    float4* xsv = (float4*)xs;
#pragma unroll
    for (int i = 0; i < 8; ++i) xsv[tid + 256 * i] = xv[tid + 256 * i];
    __syncthreads();

    const int rg = tid >> 5;   // 0..7  -> rows rg*8 .. rg*8+7
    const int cg = tid & 31;   // 0..31 -> cols j2*128 + cg*4 + {0..3}, j2=0..3

    float acc[8][16];
#pragma unroll
    for (int j2 = 0; j2 < 4; ++j2) {
        float4 bb = *(const float4*)&bias[j2 * 128 + cg * 4];
#pragma unroll
        for (int r = 0; r < 8; ++r) {
            acc[r][j2 * 4 + 0] = bb.x; acc[r][j2 * 4 + 1] = bb.y;
            acc[r][j2 * 4 + 2] = bb.z; acc[r][j2 * 4 + 3] = bb.w;
        }
    }

#pragma unroll 2
    for (int k = 0; k < 128; ++k) {
        float4 w0 = *(const float4*)&Wx[(size_t)k * G_ + 0 * 128 + cg * 4];
        float4 w1 = *(const float4*)&Wx[(size_t)k * G_ + 1 * 128 + cg * 4];
        float4 w2 = *(const float4*)&Wx[(size_t)k * G_ + 2 * 128 + cg * 4];
        float4 w3 = *(const float4*)&Wx[(size_t)k * G_ + 3 * 128 + cg * 4];
#pragma unroll
        for (int r = 0; r < 8; ++r) {
            float xval = xs[(rg * 8 + r) * 128 + k];  // broadcast read
            acc[r][0]  = fmaf(xval, w0.x, acc[r][0]);
            acc[r][1]  = fmaf(xval, w0.y, acc[r][1]);
            acc[r][2]  = fmaf(xval, w0.z, acc[r][2]);
            acc[r][3]  = fmaf(xval, w0.w, acc[r][3]);
            acc[r][4]  = fmaf(xval, w1.x, acc[r][4]);
            acc[r][5]  = fmaf(xval, w1.y, acc[r][5]);
            acc[r][6]  = fmaf(xval, w1.z, acc[r][6]);
            acc[r][7]  = fmaf(xval, w1.w, acc[r][7]);
            acc[r][8]  = fmaf(xval, w2.x, acc[r][8]);
            acc[r][9]  = fmaf(xval, w2.y, acc[r][9]);
            acc[r][10] = fmaf(xval, w2.z, acc[r][10]);
            acc[r][11] = fmaf(xval, w2.w, acc[r][11]);
            acc[r][12] = fmaf(xval, w3.x, acc[r][12]);
            acc[r][13] = fmaf(xval, w3.y, acc[r][13]);
            acc[r][14] = fmaf(xval, w3.z, acc[r][14]);
            acc[r][15] = fmaf(xval, w3.w, acc[r][15]);
        }
    }

#pragma unroll
    for (int r = 0; r < 8; ++r) {
#pragma unroll
        for (int j2 = 0; j2 < 4; ++j2) {
            float4 v;
            v.x = acc[r][j2 * 4 + 0]; v.y = acc[r][j2 * 4 + 1];
            v.z = acc[r][j2 * 4 + 2]; v.w = acc[r][j2 * 4 + 3];
            *(float4*)&xg[((size_t)block_row + rg * 8 + r) * G_ + j2 * 128 + cg * 4] = v;
        }
    }
}

// ---------------- Kernel 2: sequential recurrence ----------------
// grid: 64 blocks (one per batch), 512 threads (one per gate column).
// Thread g holds Wh[:,g] in 128 VGPRs. h in LDS, c in regs of threads 0..127.
__global__ void __launch_bounds__(512, 2)
lstm_rnn_kernel(const float* __restrict__ xg, const float* __restrict__ Wh,
                float* __restrict__ hs, float* __restrict__ cs,
                float* __restrict__ hstate, float* __restrict__ cstate,
                int t0, int C) {
    const int b = blockIdx.x;
    const int g = threadIdx.x;  // 0..511

    __shared__ __align__(16) float h_lds[H_];
    __shared__ __align__(16) float g_lds[G_];

    // one-time: load this thread's Wh column into registers (coalesced across lanes)
    float wh[128];
#pragma unroll
    for (int k = 0; k < 128; ++k) wh[k] = Wh[(size_t)k * G_ + g];

    float c = 0.0f;
    if (g < H_) {
        float hv = 0.0f;
        if (t0 > 0) { hv = hstate[b * H_ + g]; c = cstate[b * H_ + g]; }
        h_lds[g] = hv;
    }
    __syncthreads();

    const float* xgb = xg + (size_t)b * C * G_;
    float xg_next = xgb[g];  // prefetch t=0

    for (int t = 0; t < C; ++t) {
        float acc = xg_next;
        if (t + 1 < C) xg_next = xgb[(size_t)(t + 1) * G_ + g];  // prefetch; waits next iter

        // acc += h . Wh[:,g]
#pragma unroll
        for (int k = 0; k < 128; k += 4) {
            float4 h4 = *(const float4*)&h_lds[k];  // broadcast ds_read_b128
            acc = fmaf(h4.x, wh[k + 0], acc);
            acc = fmaf(h4.y, wh[k + 1], acc);
            acc = fmaf(h4.z, wh[k + 2], acc);
            acc = fmaf(h4.w, wh[k + 3], acc);
        }

        g_lds[g] = acc;
        __syncthreads();

        if (g < H_) {
            float gi = g_lds[g];
            float gf = g_lds[g + 128];
            float gg = g_lds[g + 256];
            float go = g_lds[g + 384];
            float iv = sigmoid_(gi);
            float fv = sigmoid_(gf);
            float gv = tanh_(gg);
            float ov = sigmoid_(go);
            c = fmaf(fv, c, iv * gv);
            float hn = ov * tanh_(c);
            h_lds[g] = hn;
            size_t off = ((size_t)b * T_ + (size_t)(t0 + t)) * H_ + g;
            hs[off] = hn;
            cs[off] = c;
        }
        __syncthreads();  // h_lds ready for next step
    }

    if (g < H_) {
        hstate[b * H_ + g] = h_lds[g];
        cstate[b * H_ + g] = c;
    }
}

extern "C" void kernel_launch(void* const* d_in, const int* in_sizes, int n_in,
                              void* d_out, int out_size, void* d_ws, size_t ws_size,
                              hipStream_t stream) {
    const float* x    = (const float*)d_in[0];  // [64,2048,128]
    const float* Wx   = (const float*)d_in[1];  // [128,512]
    const float* Wh   = (const float*)d_in[2];  // [128,512]
    const float* bias = (const float*)d_in[3];  // [512]

    float* hs = (float*)d_out;                         // [64,2048,128]
    float* cs = hs + (size_t)B_ * T_ * H_;             // [64,2048,128]

    float* hstate = (float*)d_ws;                      // [64,128]
    float* cstate = hstate + B_ * H_;                  // [64,128]
    float* xg     = cstate + B_ * H_;                  // chunk scratch [B][C][512]

    const size_t state_floats = (size_t)2 * B_ * H_;   // 16384 floats
    size_t avail_bytes = (ws_size > state_floats * 4) ? (ws_size - state_floats * 4) : 0;
    const size_t bytes_per_t = (size_t)B_ * G_ * sizeof(float);  // 131072 B per timestep

    int C = (int)(avail_bytes / bytes_per_t);
    if (C > T_) C = T_;
    C &= ~63;            // multiple of 64 (GEMM tiling requirement)
    if (C < 64) C = 64;  // minimum; needs ~8.5 MB of ws

    for (int t0 = 0; t0 < T_; t0 += C) {
        int Ci = (T_ - t0 < C) ? (T_ - t0) : C;
        dim3 ggrid((B_ * Ci) / 64);
        xg_gemm_kernel<<<ggrid, 256, 0, stream>>>(x, Wx, bias, xg, t0, Ci);
        lstm_rnn_kernel<<<B_, G_, 0, stream>>>(xg, Wh, hs, cs, hstate, cstate, t0, Ci);
    }
}